// Round 15
// baseline (306.306 us; speedup 1.0000x reference)
//
#include <hip/hip_runtime.h>
#include <math.h>

#define N_NODES 100000
#define N_EDGES 1600000
#define CHUNK 4096
#define NBLK_P ((N_EDGES + CHUNK - 1) / CHUNK)  // 391
#define NPAD 100064                          // 64-row padded for GEMM staging
#define BSHIFT 8                             // 256 nodes per bucket
#define NBUCK ((N_NODES + 255) / 256)        // 391 buckets
#define BCAP 6144                            // LDS record capacity per bucket

typedef __attribute__((ext_vector_type(8))) short bf16x8;
typedef __attribute__((ext_vector_type(4))) float f32x4;
typedef __attribute__((ext_vector_type(2))) float f32x2;

__device__ __forceinline__ unsigned short f2bf(float f) {
    unsigned int u = __builtin_bit_cast(unsigned int, f);
    u += 0x7fffu + ((u >> 16) & 1u);          // RNE
    return (unsigned short)(u >> 16);
}
// fp8 e4m3 (OCP) encode/decode via gfx950 hardware cvt
__device__ __forceinline__ unsigned char f2fp8(float f) {
    return (unsigned char)(__builtin_amdgcn_cvt_pk_fp8_f32(f, f, 0, false) & 0xff);
}
__device__ __forceinline__ f32x2 fp8x2f(unsigned short u) {   // 2 fp8 -> 2 f32
    return __builtin_amdgcn_cvt_pk_f32_fp8((int)u, false);
}

// ---------------- bucket count only (LDS atomics) ----------------

__global__ __launch_bounds__(1024) void edge_count_kernel(const int* __restrict__ dst,
                                                          int* __restrict__ bcnt) {
    __shared__ int lh[NBUCK];
    int tid = threadIdx.x;
    if (tid < NBUCK) lh[tid] = 0;
    __syncthreads();
    long base = (long)blockIdx.x * CHUNK;
#pragma unroll
    for (int p = 0; p < CHUNK; p += 1024) {
        long e = base + p + tid;
        if (e < N_EDGES) atomicAdd(&lh[dst[e] >> BSHIFT], 1);
    }
    __syncthreads();
    if (tid < NBUCK) bcnt[tid * NBLK_P + blockIdx.x] = lh[tid];
}

// ---------------- bucket scan over blocks (one wave per bucket) ----------------

__global__ void bucket_scan_kernel(int* __restrict__ bcnt, int* __restrict__ btot) {
    int bu = blockIdx.x, lane = threadIdx.x;   // 64 threads
    int base = 0;
    for (int i0 = 0; i0 < NBLK_P; i0 += 64) {
        int i = i0 + lane;
        int v = (i < NBLK_P) ? bcnt[bu * NBLK_P + i] : 0;
        int orig = v;
#pragma unroll
        for (int off = 1; off < 64; off <<= 1) {
            int t = __shfl_up(v, off);
            if (lane >= off) v += t;
        }
        if (i < NBLK_P) bcnt[bu * NBLK_P + i] = base + v - orig;
        base += __shfl(v, 63);
    }
    if (lane == 0) btot[bu] = base;
}

// parallel exclusive scan over NBUCK totals (single 512-thread block)
__global__ void bbase_scan_kernel(const int* __restrict__ btot, int* __restrict__ bbase) {
    __shared__ int tmp[512];
    int i = threadIdx.x;
    int v = (i < NBUCK) ? btot[i] : 0;
    tmp[i] = v;
    __syncthreads();
    for (int off = 1; off < 512; off <<= 1) {
        int t = (i >= off) ? tmp[i - off] : 0;
        __syncthreads();
        tmp[i] += t;
        __syncthreads();
    }
    if (i < NBUCK) bbase[i] = tmp[i] - v;
}

// ---------------- partition edges; record packed: src | (d&255)<<17 ----------------

__global__ __launch_bounds__(1024) void part_scatter_kernel(
        const int* __restrict__ src, const int* __restrict__ dst,
        const int* __restrict__ bcnt, const int* __restrict__ bbase,
        int* __restrict__ part) {
    __shared__ int lh[NBUCK];
    int tid = threadIdx.x;
    if (tid < NBUCK) lh[tid] = 0;
    __syncthreads();
    long base = (long)blockIdx.x * CHUNK;
#pragma unroll
    for (int p = 0; p < CHUNK; p += 1024) {
        long e = base + p + tid;
        if (e < N_EDGES) {
            int s = src[e], d = dst[e];
            int bu = d >> BSHIFT;
            int lr = atomicAdd(&lh[bu], 1);
            int pos = bbase[bu] + bcnt[bu * NBLK_P + blockIdx.x] + lr;
            part[pos] = s | ((d & 255) << 17);
        }
    }
}

// ---------------- per-bucket degrees -> rowp + dinv (LDS count + local scan) ----------------

__global__ __launch_bounds__(512) void bucket_deg_kernel(
        const int* __restrict__ part, const int* __restrict__ bbase,
        const int* __restrict__ btot, int* __restrict__ rowp,
        float* __restrict__ dinv) {
    __shared__ int lcnt[256];
    __shared__ int lscan[256];
    int b = blockIdx.x;
    int node0 = b << BSHIFT;
    int start = bbase[b];
    int cnt = btot[b];
    int tid = threadIdx.x;
    if (tid < 256) lcnt[tid] = 0;
    __syncthreads();
    for (int e = tid; e < cnt; e += 512)
        atomicAdd(&lcnt[part[start + e] >> 17], 1);
    __syncthreads();
    int v = 0;
    if (tid < 256) { v = lcnt[tid]; lscan[tid] = v; }
    __syncthreads();
    for (int off = 1; off < 256; off <<= 1) {
        int t = (tid < 256 && tid >= off) ? lscan[tid - off] : 0;
        __syncthreads();
        if (tid < 256) lscan[tid] += t;
        __syncthreads();
    }
    if (tid < 256) {
        int n = node0 + tid;
        if (n < N_NODES) {
            rowp[n] = start + lscan[tid] - v;      // exclusive prefix
            dinv[n] = rsqrtf(1.0f + (float)v);     // +1 self-loop
        }
    }
    if (b == NBUCK - 1 && tid == 0) rowp[N_NODES] = N_EDGES;
}

// ---------------- final scatter, LDS-staged per bucket: coalesced sedge writes ----------------

__global__ __launch_bounds__(512) void final_scatter_lds_kernel(
        const int* __restrict__ part, const float* __restrict__ dinv,
        const int* __restrict__ rowp, const int* __restrict__ bbase,
        const int* __restrict__ btot, int2* __restrict__ sedge) {
    __shared__ int lcurs[256];
    __shared__ int2 buf[BCAP];
    int b = blockIdx.x;
    int node0 = b << BSHIFT;
    int start = bbase[b];
    int cnt = btot[b];
    int tid = threadIdx.x;
    if (tid < 256) {
        int n = node0 + tid;
        lcurs[tid] = (n < N_NODES) ? (rowp[n] - start) : cnt;
    }
    __syncthreads();
    for (int e = tid; e < cnt; e += 512) {
        int r = part[start + e];
        int s = r & 0x1FFFF;
        int lpos = atomicAdd(&lcurs[r >> 17], 1);
        int2 rec; rec.x = s; rec.y = __float_as_int(dinv[s]);
        if (lpos < BCAP) buf[lpos] = rec;
        else sedge[start + lpos] = rec;   // statistical-impossibility fallback
    }
    __syncthreads();
    int lim = min(cnt, BCAP);
    for (int e = tid; e < lim; e += 512)
        sedge[start + e] = buf[e];
}

// ---------------- conversions ----------------

// x (f32) -> fp8 e4m3 (gather table for layer-1 agg)
__global__ void cvt_x_kernel(const float* __restrict__ x, unsigned char* __restrict__ xb) {
    long i = (long)blockIdx.x * blockDim.x + threadIdx.x;   // over n/4
    if (i >= (long)N_NODES * 128 / 4) return;
    float4 v = ((const float4*)x)[i];
    int p0 = __builtin_amdgcn_cvt_pk_fp8_f32(v.x, v.y, 0, false);
    int p1 = __builtin_amdgcn_cvt_pk_fp8_f32(v.z, v.w, 0, false);
    ((unsigned int*)xb)[i] = ((unsigned int)p0 & 0xffffu) | ((unsigned int)p1 << 16);
}

// all three weights, transposed+converted: Wt[m][k] = bf16(W[k][m])
__global__ void cvt_w_all_kernel(const float* __restrict__ W1, const float* __restrict__ W2,
                                 const float* __restrict__ W3,
                                 unsigned short* __restrict__ Wt1,
                                 unsigned short* __restrict__ Wt2,
                                 unsigned short* __restrict__ Wt3) {
    int i = blockIdx.x * blockDim.x + threadIdx.x;
    if (i < 32768) {                       // W1: [128][256]
        int k = i >> 8, m = i & 255;
        Wt1[m * 128 + k] = f2bf(W1[i]);
    } else if (i < 65536) {                // W2: [256][128]
        int j = i - 32768;
        int k = j >> 7, m = j & 127;
        Wt2[m * 256 + k] = f2bf(W2[j]);
    } else if (i < 73728) {                // W3: [128][64]
        int j = i - 65536;
        int k = j >> 6, m = j & 63;
        Wt3[m * 128 + k] = f2bf(W3[j]);
    }
}

// ---------------- CSR gather aggregation (fp8 in, bf16/f32 out) ----------------
// one wave per dst node; multi-edge per wave: C=128 -> 2 edges (32-lane halves,
// 4B/lane), C=64 -> 4 edges (16-lane quads, 4B/lane). Cross-group shfl combine.

template<int C, bool BIAS, bool RELU, bool LOGSM, bool OUTF32>
__global__ __launch_bounds__(64) void agg_csr_kernel(
                               const unsigned char* __restrict__ h8,
                               const float* __restrict__ dinv,
                               const int* __restrict__ rowptr,
                               const int2* __restrict__ sedge,
                               const float* __restrict__ bias, void* __restrict__ outv) {
    int gw = blockIdx.x;
    int lane = threadIdx.x;

    float di = dinv[gw];
    int st = rowptr[gw];
    int cnt = rowptr[gw + 1] - st;
    float a0, a1, a2, a3;

    if constexpr (C == 128) {
        int half = lane >> 5, l32 = lane & 31;
        // self-loop (half 0 only, to avoid double count after combine)
        {
            unsigned int u = ((const unsigned int*)(h8 + (long)gw * 128))[l32];
            f32x2 lo = fp8x2f((unsigned short)(u & 0xffff));
            f32x2 hi = fp8x2f((unsigned short)(u >> 16));
            float w = (half == 0) ? di : 0.0f;
            a0 = w * lo.x; a1 = w * lo.y; a2 = w * hi.x; a3 = w * hi.y;
        }
        int k = 0;
        for (; k + 16 <= cnt; k += 16) {     // 8 pairs in flight
            int2 r[8];
#pragma unroll
            for (int j = 0; j < 8; ++j) r[j] = sedge[st + k + 2 * j + half];
            unsigned int u[8];
#pragma unroll
            for (int j = 0; j < 8; ++j)
                u[j] = ((const unsigned int*)(h8 + (long)r[j].x * 128))[l32];
#pragma unroll
            for (int j = 0; j < 8; ++j) {
                float w = __int_as_float(r[j].y);
                f32x2 lo = fp8x2f((unsigned short)(u[j] & 0xffff));
                f32x2 hi = fp8x2f((unsigned short)(u[j] >> 16));
                a0 += w * lo.x; a1 += w * lo.y; a2 += w * hi.x; a3 += w * hi.y;
            }
        }
        for (; k + 2 <= cnt; k += 2) {
            int2 r = sedge[st + k + half];
            unsigned int u = ((const unsigned int*)(h8 + (long)r.x * 128))[l32];
            float w = __int_as_float(r.y);
            f32x2 lo = fp8x2f((unsigned short)(u & 0xffff));
            f32x2 hi = fp8x2f((unsigned short)(u >> 16));
            a0 += w * lo.x; a1 += w * lo.y; a2 += w * hi.x; a3 += w * hi.y;
        }
        if (k < cnt) {                        // odd leftover: half 0 only
            int2 r = sedge[st + k];
            unsigned int u = ((const unsigned int*)(h8 + (long)r.x * 128))[l32];
            float w = (half == 0) ? __int_as_float(r.y) : 0.0f;
            f32x2 lo = fp8x2f((unsigned short)(u & 0xffff));
            f32x2 hi = fp8x2f((unsigned short)(u >> 16));
            a0 += w * lo.x; a1 += w * lo.y; a2 += w * hi.x; a3 += w * hi.y;
        }
        // combine halves
        a0 += __shfl_xor(a0, 32); a1 += __shfl_xor(a1, 32);
        a2 += __shfl_xor(a2, 32); a3 += __shfl_xor(a3, 32);
        a0 *= di; a1 *= di; a2 *= di; a3 *= di;
        if constexpr (BIAS) {
            float4 b = *(const float4*)(bias + l32 * 4);
            a0 += b.x; a1 += b.y; a2 += b.z; a3 += b.w;
        }
        if constexpr (RELU) {
            a0 = fmaxf(a0, 0.f); a1 = fmaxf(a1, 0.f);
            a2 = fmaxf(a2, 0.f); a3 = fmaxf(a3, 0.f);
        }
        if (lane < 32) {   // bf16 out: 4 bf16 = 8B per lane, 256B row
            uint2 p;
            p.x = (unsigned int)f2bf(a0) | ((unsigned int)f2bf(a1) << 16);
            p.y = (unsigned int)f2bf(a2) | ((unsigned int)f2bf(a3) << 16);
            *(uint2*)((unsigned short*)outv + (long)gw * 128 + l32 * 4) = p;
        }
    } else {   // C == 64
        int quad = lane >> 4, l16 = lane & 15;
        {
            unsigned int u = ((const unsigned int*)(h8 + (long)gw * 64))[l16];
            f32x2 lo = fp8x2f((unsigned short)(u & 0xffff));
            f32x2 hi = fp8x2f((unsigned short)(u >> 16));
            float w = (quad == 0) ? di : 0.0f;
            a0 = w * lo.x; a1 = w * lo.y; a2 = w * hi.x; a3 = w * hi.y;
        }
        int k = 0;
        for (; k + 16 <= cnt; k += 16) {     // 4 quads x 4-deep = 16 edges
            int2 r[4];
#pragma unroll
            for (int j = 0; j < 4; ++j) r[j] = sedge[st + k + 4 * j + quad];
            unsigned int u[4];
#pragma unroll
            for (int j = 0; j < 4; ++j)
                u[j] = ((const unsigned int*)(h8 + (long)r[j].x * 64))[l16];
#pragma unroll
            for (int j = 0; j < 4; ++j) {
                float w = __int_as_float(r[j].y);
                f32x2 lo = fp8x2f((unsigned short)(u[j] & 0xffff));
                f32x2 hi = fp8x2f((unsigned short)(u[j] >> 16));
                a0 += w * lo.x; a1 += w * lo.y; a2 += w * hi.x; a3 += w * hi.y;
            }
        }
        for (; k + 4 <= cnt; k += 4) {
            int2 r = sedge[st + k + quad];
            unsigned int u = ((const unsigned int*)(h8 + (long)r.x * 64))[l16];
            float w = __int_as_float(r.y);
            f32x2 lo = fp8x2f((unsigned short)(u & 0xffff));
            f32x2 hi = fp8x2f((unsigned short)(u >> 16));
            a0 += w * lo.x; a1 += w * lo.y; a2 += w * hi.x; a3 += w * hi.y;
        }
        {
            int rem = cnt - k;                // 0..3
            if (rem > 0) {
                int idx = st + k + min(quad, rem - 1);
                int2 r = sedge[idx];
                unsigned int u = ((const unsigned int*)(h8 + (long)r.x * 64))[l16];
                float w = (quad < rem) ? __int_as_float(r.y) : 0.0f;
                f32x2 lo = fp8x2f((unsigned short)(u & 0xffff));
                f32x2 hi = fp8x2f((unsigned short)(u >> 16));
                a0 += w * lo.x; a1 += w * lo.y; a2 += w * hi.x; a3 += w * hi.y;
            }
        }
        // combine quads
        a0 += __shfl_xor(a0, 32); a1 += __shfl_xor(a1, 32);
        a2 += __shfl_xor(a2, 32); a3 += __shfl_xor(a3, 32);
        a0 += __shfl_xor(a0, 16); a1 += __shfl_xor(a1, 16);
        a2 += __shfl_xor(a2, 16); a3 += __shfl_xor(a3, 16);
        a0 *= di; a1 *= di; a2 *= di; a3 *= di;
        if constexpr (BIAS) {
            float4 b = *(const float4*)(bias + l16 * 4);
            a0 += b.x; a1 += b.y; a2 += b.z; a3 += b.w;
        }
        if constexpr (RELU) {
            a0 = fmaxf(a0, 0.f); a1 = fmaxf(a1, 0.f);
            a2 = fmaxf(a2, 0.f); a3 = fmaxf(a3, 0.f);
        }
        if constexpr (LOGSM) {
            float m = fmaxf(fmaxf(a0, a1), fmaxf(a2, a3));
#pragma unroll
            for (int o = 8; o > 0; o >>= 1) m = fmaxf(m, __shfl_xor(m, o));
            float s = expf(a0 - m) + expf(a1 - m) + expf(a2 - m) + expf(a3 - m);
#pragma unroll
            for (int o = 8; o > 0; o >>= 1) s += __shfl_xor(s, o);
            float ls = m + logf(s);
            a0 -= ls; a1 -= ls; a2 -= ls; a3 -= ls;
        }
        if (lane < 16) {
            if constexpr (OUTF32) {
                float4 v; v.x = a0; v.y = a1; v.z = a2; v.w = a3;
                *(float4*)((float*)outv + (long)gw * 64 + l16 * 4) = v;
            } else {
                uint2 p;
                p.x = (unsigned int)f2bf(a0) | ((unsigned int)f2bf(a1) << 16);
                p.y = (unsigned int)f2bf(a2) | ((unsigned int)f2bf(a3) << 16);
                *(uint2*)((unsigned short*)outv + (long)gw * 64 + l16 * 4) = p;
            }
        }
    }
}

// ---------------- bf16 MFMA GEMM, 64 x full-M tile; bf16 or fp8 output ----------------
template<int K, int M, bool BIAS, bool RELU, bool OUT8>
__global__ __launch_bounds__(256) void gemm_mfma_kernel(
        const unsigned short* __restrict__ A,   // [NPAD][K] bf16
        const unsigned short* __restrict__ Bt,  // [M][K] bf16
        const float* __restrict__ bias,         // [M]
        void* __restrict__ Cv,                  // [NPAD][M] bf16 or fp8
        int N) {
    constexpr int KC = K / 8;                    // 16B chunks per row
    constexpr int NT = M / 64;                   // col subtiles per wave (M/4/16)
    __shared__ unsigned short As[64 * K];

    int tid = threadIdx.x;
    int row0 = blockIdx.x * 64;
    const unsigned short* Ap = A + (long)row0 * K;

    // stage A panel; LDS byte = (c*16) ^ ((row&7)<<4)
    for (int c = tid; c < 64 * KC; c += 256) {
        int r = c / KC;
        unsigned int swz = ((unsigned int)c * 16u) ^ ((unsigned int)(r & 7) << 4);
        *(bf16x8*)((char*)As + swz) = *(const bf16x8*)(Ap + c * 8);
    }
    __syncthreads();

    int lane = tid & 63;
    int wv = tid >> 6;
    int lr = lane & 15;
    int kg = lane >> 4;                 // k-group: k = kg*8 + j
    int colbase = wv * (M / 4);

    const unsigned short* bp[NT];
#pragma unroll
    for (int ni = 0; ni < NT; ++ni)
        bp[ni] = Bt + (size_t)(colbase + ni * 16 + lr) * K + kg * 8;

    f32x4 acc[4][NT] = {};

    for (int k0 = 0; k0 < K; k0 += 32) {
        bf16x8 a[4], b[NT];
#pragma unroll
        for (int mi = 0; mi < 4; ++mi) {
            int r = mi * 16 + lr;
            unsigned int byteo = (unsigned int)((r * K + k0 + kg * 8) * 2);
            byteo ^= (unsigned int)((r & 7) << 4);
            a[mi] = *(const bf16x8*)((const char*)As + byteo);
        }
#pragma unroll
        for (int ni = 0; ni < NT; ++ni)
            b[ni] = *(const bf16x8*)(bp[ni] + k0);
#pragma unroll
        for (int mi = 0; mi < 4; ++mi)
#pragma unroll
            for (int ni = 0; ni < NT; ++ni)
                acc[mi][ni] = __builtin_amdgcn_mfma_f32_16x16x32_bf16(
                    a[mi], b[ni], acc[mi][ni], 0, 0, 0);
    }

    // epilogue: C/D layout col=lane&15, row=(lane>>4)*4+i
#pragma unroll
    for (int mi = 0; mi < 4; ++mi) {
#pragma unroll
        for (int ni = 0; ni < NT; ++ni) {
            int col = colbase + ni * 16 + lr;
            float bv = BIAS ? bias[col] : 0.0f;
#pragma unroll
            for (int i = 0; i < 4; ++i) {
                int row = row0 + mi * 16 + kg * 4 + i;
                if (row < N) {
                    float v = acc[mi][ni][i] + bv;
                    if (RELU) v = fmaxf(v, 0.0f);
                    if constexpr (OUT8)
                        ((unsigned char*)Cv)[(long)row * M + col] = f2fp8(v);
                    else
                        ((unsigned short*)Cv)[(long)row * M + col] = f2bf(v);
                }
            }
        }
    }
}

// ---------------- launch ----------------

extern "C" void kernel_launch(void* const* d_in, const int* in_sizes, int n_in,
                              void* d_out, int out_size, void* d_ws, size_t ws_size,
                              hipStream_t stream) {
    const float* x  = (const float*)d_in[0];
    const int* edge = (const int*)d_in[1];
    const float* W1 = (const float*)d_in[2];
    const float* b1 = (const float*)d_in[3];
    const float* W2 = (const float*)d_in[4];
    const float* b2 = (const float*)d_in[5];
    const float* W3 = (const float*)d_in[6];
    const float* b3 = (const float*)d_in[7];
    float* out = (float*)d_out;

    const int* src = edge;
    const int* dst = edge + N_EDGES;

    // workspace layout (float-element offsets)
    float* ws    = (float*)d_ws;
    float* dinv  = ws;                                   // N
    int*   rowp  = (int*)(ws + 100000);                  // N+1 (alloc 100352)
    int*   btot  = (int*)(ws + 200352);                  // 391 (alloc 512)
    int*   bbase = (int*)(ws + 200864);                  // 391 (alloc 512)
    int*   bcnt  = (int*)(ws + 201376);                  // 391*391=152881 (alloc 153600)
    int2*  sedge = (int2*)(ws + 354976);                 // E*2 ints -> ends 3554976
    unsigned char*  X8 = (unsigned char*)(ws + 3554976);     // [NPAD][128] fp8 -> 3202048 f
    unsigned short* B1 = (unsigned short*)(ws + 6757024);    // [NPAD][128] bf16 -> 6404096 f
    unsigned short* B2 = (unsigned short*)(ws + 13161120);   // [NPAD][256] bf16 -> 12808192 f
    unsigned char*  Q2 = (unsigned char*)(ws + 25969312);    // [NPAD][128] fp8 -> 3202048 f
    unsigned short* Wt1 = (unsigned short*)(ws + 29171360);  // [256][128]
    unsigned short* Wt2 = Wt1 + 128 * 256;                   // [128][256]
    unsigned short* Wt3 = Wt2 + 256 * 128;                   // [64][128]
    int*   part  = (int*)B2;   // scratch reuse: consumed before gemm1 writes B2

    const int BT = 256;
    int gRows = (N_NODES + 63) / 64;   // 1563

    // --- bucket counts (reads dst once; LDS-only atomics) ---
    edge_count_kernel<<<NBLK_P, 1024, 0, stream>>>(dst, bcnt);

    // --- bucket scans + partition (packed 32-bit records) ---
    bucket_scan_kernel<<<NBUCK, 64, 0, stream>>>(bcnt, btot);
    bbase_scan_kernel<<<1, 512, 0, stream>>>(btot, bbase);
    part_scatter_kernel<<<NBLK_P, 1024, 0, stream>>>(src, dst, bcnt, bbase, part);

    // --- per-bucket degrees -> rowp + dinv; then coalesced CSR scatter ---
    bucket_deg_kernel<<<NBUCK, 512, 0, stream>>>(part, bbase, btot, rowp, dinv);
    final_scatter_lds_kernel<<<NBUCK, 512, 0, stream>>>(part, dinv, rowp, bbase, btot, sedge);

    // --- conversions ---
    cvt_x_kernel<<<(int)(((long)N_NODES * 128 / 4 + BT - 1) / BT), BT, 0, stream>>>(x, X8);
    cvt_w_all_kernel<<<(73728 + BT - 1) / BT, BT, 0, stream>>>(W1, W2, W3, Wt1, Wt2, Wt3);

    // --- layer 1: agg(x fp8) [X8->B1 bf16], gemm 128->256 +b1 +relu [B1->B2 bf16] ---
    agg_csr_kernel<128, false, false, false, false><<<N_NODES, 64, 0, stream>>>(
        X8, dinv, rowp, sedge, nullptr, B1);
    gemm_mfma_kernel<128, 256, true, true, false><<<gRows, BT, 0, stream>>>(
        B1, Wt1, b1, B2, N_NODES);

    // --- layer 2: gemm 256->128 [B2->Q2 fp8], agg +b2 +relu [Q2->B1 bf16] ---
    gemm_mfma_kernel<256, 128, false, false, true><<<gRows, BT, 0, stream>>>(
        B2, Wt2, nullptr, Q2, N_NODES);
    agg_csr_kernel<128, true, true, false, false><<<N_NODES, 64, 0, stream>>>(
        Q2, dinv, rowp, sedge, b2, B1);

    // --- layer 3: gemm 128->64 [B1->Q2 fp8], agg +b3 +relu +logsm [Q2->out f32] ---
    gemm_mfma_kernel<128, 64, false, false, true><<<gRows, BT, 0, stream>>>(
        B1, Wt3, nullptr, Q2, N_NODES);
    agg_csr_kernel<64, true, true, true, true><<<N_NODES, 64, 0, stream>>>(
        Q2, dinv, rowp, sedge, b3, out);

    (void)in_sizes; (void)n_in; (void)out_size; (void)ws_size;
}

// Round 16
// 275.594 us; speedup vs baseline: 1.1114x; 1.1114x over previous
//
#include <hip/hip_runtime.h>
#include <math.h>

#define N_NODES 100000
#define N_EDGES 1600000
#define CHUNK 4096
#define NBLK_P ((N_EDGES + CHUNK - 1) / CHUNK)  // 391
#define NPAD 100064                          // 64-row padded for GEMM staging
#define BSHIFT 8                             // 256 nodes per bucket
#define NBUCK ((N_NODES + 255) / 256)        // 391 buckets
#define BCAP 6144                            // LDS record capacity per bucket

typedef __attribute__((ext_vector_type(8))) short bf16x8;
typedef __attribute__((ext_vector_type(4))) float f32x4;
typedef __attribute__((ext_vector_type(2))) float f32x2;

__device__ __forceinline__ unsigned short f2bf(float f) {
    unsigned int u = __builtin_bit_cast(unsigned int, f);
    u += 0x7fffu + ((u >> 16) & 1u);          // RNE
    return (unsigned short)(u >> 16);
}
// fp8 e4m3 (OCP) encode/decode via gfx950 hardware cvt
__device__ __forceinline__ unsigned char f2fp8(float f) {
    return (unsigned char)(__builtin_amdgcn_cvt_pk_fp8_f32(f, f, 0, false) & 0xff);
}
__device__ __forceinline__ f32x2 fp8x2f(unsigned short u) {   // 2 fp8 -> 2 f32
    return __builtin_amdgcn_cvt_pk_f32_fp8((int)u, false);
}
__device__ __forceinline__ float fp8f(unsigned char u) {
    return __builtin_amdgcn_cvt_f32_fp8((int)u, 0);
}

// ---------------- bucket count only (LDS atomics) ----------------

__global__ __launch_bounds__(1024) void edge_count_kernel(const int* __restrict__ dst,
                                                          int* __restrict__ bcnt) {
    __shared__ int lh[NBUCK];
    int tid = threadIdx.x;
    if (tid < NBUCK) lh[tid] = 0;
    __syncthreads();
    long base = (long)blockIdx.x * CHUNK;
#pragma unroll
    for (int p = 0; p < CHUNK; p += 1024) {
        long e = base + p + tid;
        if (e < N_EDGES) atomicAdd(&lh[dst[e] >> BSHIFT], 1);
    }
    __syncthreads();
    if (tid < NBUCK) bcnt[tid * NBLK_P + blockIdx.x] = lh[tid];
}

// ---------------- bucket scan over blocks (one wave per bucket) ----------------

__global__ void bucket_scan_kernel(int* __restrict__ bcnt, int* __restrict__ btot) {
    int bu = blockIdx.x, lane = threadIdx.x;   // 64 threads
    int base = 0;
    for (int i0 = 0; i0 < NBLK_P; i0 += 64) {
        int i = i0 + lane;
        int v = (i < NBLK_P) ? bcnt[bu * NBLK_P + i] : 0;
        int orig = v;
#pragma unroll
        for (int off = 1; off < 64; off <<= 1) {
            int t = __shfl_up(v, off);
            if (lane >= off) v += t;
        }
        if (i < NBLK_P) bcnt[bu * NBLK_P + i] = base + v - orig;
        base += __shfl(v, 63);
    }
    if (lane == 0) btot[bu] = base;
}

// parallel exclusive scan over NBUCK totals (single 512-thread block)
__global__ void bbase_scan_kernel(const int* __restrict__ btot, int* __restrict__ bbase) {
    __shared__ int tmp[512];
    int i = threadIdx.x;
    int v = (i < NBUCK) ? btot[i] : 0;
    tmp[i] = v;
    __syncthreads();
    for (int off = 1; off < 512; off <<= 1) {
        int t = (i >= off) ? tmp[i - off] : 0;
        __syncthreads();
        tmp[i] += t;
        __syncthreads();
    }
    if (i < NBUCK) bbase[i] = tmp[i] - v;
}

// ---------------- partition edges; record packed: src | (d&255)<<17 ----------------

__global__ __launch_bounds__(1024) void part_scatter_kernel(
        const int* __restrict__ src, const int* __restrict__ dst,
        const int* __restrict__ bcnt, const int* __restrict__ bbase,
        int* __restrict__ part) {
    __shared__ int lh[NBUCK];
    int tid = threadIdx.x;
    if (tid < NBUCK) lh[tid] = 0;
    __syncthreads();
    long base = (long)blockIdx.x * CHUNK;
#pragma unroll
    for (int p = 0; p < CHUNK; p += 1024) {
        long e = base + p + tid;
        if (e < N_EDGES) {
            int s = src[e], d = dst[e];
            int bu = d >> BSHIFT;
            int lr = atomicAdd(&lh[bu], 1);
            int pos = bbase[bu] + bcnt[bu * NBLK_P + blockIdx.x] + lr;
            part[pos] = s | ((d & 255) << 17);
        }
    }
}

// ---------------- per-bucket degrees -> rowp + dinv (LDS count + local scan) ----------------

__global__ __launch_bounds__(512) void bucket_deg_kernel(
        const int* __restrict__ part, const int* __restrict__ bbase,
        const int* __restrict__ btot, int* __restrict__ rowp,
        float* __restrict__ dinv) {
    __shared__ int lcnt[256];
    __shared__ int lscan[256];
    int b = blockIdx.x;
    int node0 = b << BSHIFT;
    int start = bbase[b];
    int cnt = btot[b];
    int tid = threadIdx.x;
    if (tid < 256) lcnt[tid] = 0;
    __syncthreads();
    for (int e = tid; e < cnt; e += 512)
        atomicAdd(&lcnt[part[start + e] >> 17], 1);
    __syncthreads();
    int v = 0;
    if (tid < 256) { v = lcnt[tid]; lscan[tid] = v; }
    __syncthreads();
    for (int off = 1; off < 256; off <<= 1) {
        int t = (tid < 256 && tid >= off) ? lscan[tid - off] : 0;
        __syncthreads();
        if (tid < 256) lscan[tid] += t;
        __syncthreads();
    }
    if (tid < 256) {
        int n = node0 + tid;
        if (n < N_NODES) {
            rowp[n] = start + lscan[tid] - v;      // exclusive prefix
            dinv[n] = rsqrtf(1.0f + (float)v);     // +1 self-loop
        }
    }
    if (b == NBUCK - 1 && tid == 0) rowp[N_NODES] = N_EDGES;
}

// ---------------- final scatter, LDS-staged per bucket: coalesced sedge writes ----------------

__global__ __launch_bounds__(512) void final_scatter_lds_kernel(
        const int* __restrict__ part, const float* __restrict__ dinv,
        const int* __restrict__ rowp, const int* __restrict__ bbase,
        const int* __restrict__ btot, int2* __restrict__ sedge) {
    __shared__ int lcurs[256];
    __shared__ int2 buf[BCAP];
    int b = blockIdx.x;
    int node0 = b << BSHIFT;
    int start = bbase[b];
    int cnt = btot[b];
    int tid = threadIdx.x;
    if (tid < 256) {
        int n = node0 + tid;
        lcurs[tid] = (n < N_NODES) ? (rowp[n] - start) : cnt;
    }
    __syncthreads();
    for (int e = tid; e < cnt; e += 512) {
        int r = part[start + e];
        int s = r & 0x1FFFF;
        int lpos = atomicAdd(&lcurs[r >> 17], 1);
        int2 rec; rec.x = s; rec.y = __float_as_int(dinv[s]);
        if (lpos < BCAP) buf[lpos] = rec;
        else sedge[start + lpos] = rec;   // statistical-impossibility fallback
    }
    __syncthreads();
    int lim = min(cnt, BCAP);
    for (int e = tid; e < lim; e += 512)
        sedge[start + e] = buf[e];
}

// ---------------- conversions ----------------

// x (f32) -> fp8 e4m3 (gather table for layer-1 agg)
__global__ void cvt_x_kernel(const float* __restrict__ x, unsigned char* __restrict__ xb) {
    long i = (long)blockIdx.x * blockDim.x + threadIdx.x;   // over n/4
    if (i >= (long)N_NODES * 128 / 4) return;
    float4 v = ((const float4*)x)[i];
    int p0 = __builtin_amdgcn_cvt_pk_fp8_f32(v.x, v.y, 0, false);
    int p1 = __builtin_amdgcn_cvt_pk_fp8_f32(v.z, v.w, 0, false);
    ((unsigned int*)xb)[i] = ((unsigned int)p0 & 0xffffu) | ((unsigned int)p1 << 16);
}

// all three weights, transposed+converted: Wt[m][k] = bf16(W[k][m])
__global__ void cvt_w_all_kernel(const float* __restrict__ W1, const float* __restrict__ W2,
                                 const float* __restrict__ W3,
                                 unsigned short* __restrict__ Wt1,
                                 unsigned short* __restrict__ Wt2,
                                 unsigned short* __restrict__ Wt3) {
    int i = blockIdx.x * blockDim.x + threadIdx.x;
    if (i < 32768) {                       // W1: [128][256]
        int k = i >> 8, m = i & 255;
        Wt1[m * 128 + k] = f2bf(W1[i]);
    } else if (i < 65536) {                // W2: [256][128]
        int j = i - 32768;
        int k = j >> 7, m = j & 127;
        Wt2[m * 256 + k] = f2bf(W2[j]);
    } else if (i < 73728) {                // W3: [128][64]
        int j = i - 65536;
        int k = j >> 6, m = j & 63;
        Wt3[m * 128 + k] = f2bf(W3[j]);
    }
}

// ---------------- CSR gather aggregation (fp8 in, bf16/f32 out) ----------------
// one wave per dst node; gathers fp8 rows (half the bytes of bf16), fp32 accum

template<int C, bool BIAS, bool RELU, bool LOGSM, bool OUTF32>
__global__ __launch_bounds__(64) void agg_csr_kernel(
                               const unsigned char* __restrict__ h8,
                               const float* __restrict__ dinv,
                               const int* __restrict__ rowptr,
                               const int2* __restrict__ sedge,
                               const float* __restrict__ bias, void* __restrict__ outv) {
    constexpr int V = C / 64;  // 2 for C=128, 1 for C=64
    int gw = blockIdx.x;
    int lane = threadIdx.x;
    if (gw >= N_NODES) return;

    float di = dinv[gw];
    int st = rowptr[gw];
    int cnt = rowptr[gw + 1] - st;
    float a0, a1 = 0.0f;
    if constexpr (V == 2) {
        unsigned short u = ((const unsigned short*)(h8 + (long)gw * C))[lane];
        f32x2 f = fp8x2f(u);
        a0 = di * f.x; a1 = di * f.y;
    } else {
        a0 = di * fp8f(h8[(long)gw * C + lane]);
    }

    int k = 0;
    // 8-deep gather block
    for (; k + 8 <= cnt; k += 8) {
        int2 r[8];
#pragma unroll
        for (int j = 0; j < 8; ++j) r[j] = sedge[st + k + j];
        if constexpr (V == 2) {
            unsigned short u[8];
#pragma unroll
            for (int j = 0; j < 8; ++j)
                u[j] = ((const unsigned short*)(h8 + (long)r[j].x * C))[lane];
#pragma unroll
            for (int j = 0; j < 8; ++j) {
                float w = __int_as_float(r[j].y);
                f32x2 f = fp8x2f(u[j]);
                a0 += w * f.x; a1 += w * f.y;
            }
        } else {
            unsigned char u[8];
#pragma unroll
            for (int j = 0; j < 8; ++j)
                u[j] = h8[(long)r[j].x * C + lane];
#pragma unroll
            for (int j = 0; j < 8; ++j)
                a0 += __int_as_float(r[j].y) * fp8f(u[j]);
        }
    }
    // 4-deep
    for (; k + 4 <= cnt; k += 4) {
        int2 r[4];
#pragma unroll
        for (int j = 0; j < 4; ++j) r[j] = sedge[st + k + j];
        if constexpr (V == 2) {
            unsigned short u[4];
#pragma unroll
            for (int j = 0; j < 4; ++j)
                u[j] = ((const unsigned short*)(h8 + (long)r[j].x * C))[lane];
#pragma unroll
            for (int j = 0; j < 4; ++j) {
                float w = __int_as_float(r[j].y);
                f32x2 f = fp8x2f(u[j]);
                a0 += w * f.x; a1 += w * f.y;
            }
        } else {
            unsigned char u[4];
#pragma unroll
            for (int j = 0; j < 4; ++j)
                u[j] = h8[(long)r[j].x * C + lane];
#pragma unroll
            for (int j = 0; j < 4; ++j)
                a0 += __int_as_float(r[j].y) * fp8f(u[j]);
        }
    }
    // tail
    for (; k < cnt; ++k) {
        int2 r = sedge[st + k];
        float w = __int_as_float(r.y);
        if constexpr (V == 2) {
            unsigned short u = ((const unsigned short*)(h8 + (long)r.x * C))[lane];
            f32x2 f = fp8x2f(u);
            a0 += w * f.x; a1 += w * f.y;
        } else {
            a0 += w * fp8f(h8[(long)r.x * C + lane]);
        }
    }

    a0 *= di; a1 *= di;
    if constexpr (BIAS) {
        if constexpr (V == 2) { a0 += bias[lane * 2]; a1 += bias[lane * 2 + 1]; }
        else a0 += bias[lane];
    }
    if constexpr (RELU) { a0 = fmaxf(a0, 0.0f); a1 = fmaxf(a1, 0.0f); }
    if constexpr (LOGSM) {  // V==1 only
        float m = a0;
#pragma unroll
        for (int o = 32; o > 0; o >>= 1) m = fmaxf(m, __shfl_xor(m, o));
        float e = expf(a0 - m), s = e;
#pragma unroll
        for (int o = 32; o > 0; o >>= 1) s += __shfl_xor(s, o);
        a0 = a0 - m - logf(s);
    }
    if constexpr (OUTF32) {
        float* out = (float*)outv;
        if constexpr (V == 2) {
            float2 r; r.x = a0; r.y = a1;
            *(float2*)(out + (long)gw * C + lane * 2) = r;
        } else {
            out[(long)gw * C + lane] = a0;
        }
    } else {
        unsigned short* out = (unsigned short*)outv;
        if constexpr (V == 2) {
            unsigned int up = (unsigned int)f2bf(a0) | ((unsigned int)f2bf(a1) << 16);
            ((unsigned int*)(out + (long)gw * C))[lane] = up;
        } else {
            out[(long)gw * C + lane] = f2bf(a0);
        }
    }
}

// ---------------- bf16 MFMA GEMM, 64 x full-M tile; bf16 or fp8 output ----------------
template<int K, int M, bool BIAS, bool RELU, bool OUT8>
__global__ __launch_bounds__(256) void gemm_mfma_kernel(
        const unsigned short* __restrict__ A,   // [NPAD][K] bf16
        const unsigned short* __restrict__ Bt,  // [M][K] bf16
        const float* __restrict__ bias,         // [M]
        void* __restrict__ Cv,                  // [NPAD][M] bf16 or fp8
        int N) {
    constexpr int KC = K / 8;                    // 16B chunks per row
    constexpr int NT = M / 64;                   // col subtiles per wave (M/4/16)
    __shared__ unsigned short As[64 * K];

    int tid = threadIdx.x;
    int row0 = blockIdx.x * 64;
    const unsigned short* Ap = A + (long)row0 * K;

    // stage A panel; LDS byte = (c*16) ^ ((row&7)<<4)
    for (int c = tid; c < 64 * KC; c += 256) {
        int r = c / KC;
        unsigned int swz = ((unsigned int)c * 16u) ^ ((unsigned int)(r & 7) << 4);
        *(bf16x8*)((char*)As + swz) = *(const bf16x8*)(Ap + c * 8);
    }
    __syncthreads();

    int lane = tid & 63;
    int wv = tid >> 6;
    int lr = lane & 15;
    int kg = lane >> 4;                 // k-group: k = kg*8 + j
    int colbase = wv * (M / 4);

    const unsigned short* bp[NT];
#pragma unroll
    for (int ni = 0; ni < NT; ++ni)
        bp[ni] = Bt + (size_t)(colbase + ni * 16 + lr) * K + kg * 8;

    f32x4 acc[4][NT] = {};

    for (int k0 = 0; k0 < K; k0 += 32) {
        bf16x8 a[4], b[NT];
#pragma unroll
        for (int mi = 0; mi < 4; ++mi) {
            int r = mi * 16 + lr;
            unsigned int byteo = (unsigned int)((r * K + k0 + kg * 8) * 2);
            byteo ^= (unsigned int)((r & 7) << 4);
            a[mi] = *(const bf16x8*)((const char*)As + byteo);
        }
#pragma unroll
        for (int ni = 0; ni < NT; ++ni)
            b[ni] = *(const bf16x8*)(bp[ni] + k0);
#pragma unroll
        for (int mi = 0; mi < 4; ++mi)
#pragma unroll
            for (int ni = 0; ni < NT; ++ni)
                acc[mi][ni] = __builtin_amdgcn_mfma_f32_16x16x32_bf16(
                    a[mi], b[ni], acc[mi][ni], 0, 0, 0);
    }

    // epilogue: C/D layout col=lane&15, row=(lane>>4)*4+i
#pragma unroll
    for (int mi = 0; mi < 4; ++mi) {
#pragma unroll
        for (int ni = 0; ni < NT; ++ni) {
            int col = colbase + ni * 16 + lr;
            float bv = BIAS ? bias[col] : 0.0f;
#pragma unroll
            for (int i = 0; i < 4; ++i) {
                int row = row0 + mi * 16 + kg * 4 + i;
                if (row < N) {
                    float v = acc[mi][ni][i] + bv;
                    if (RELU) v = fmaxf(v, 0.0f);
                    if constexpr (OUT8)
                        ((unsigned char*)Cv)[(long)row * M + col] = f2fp8(v);
                    else
                        ((unsigned short*)Cv)[(long)row * M + col] = f2bf(v);
                }
            }
        }
    }
}

// ---------------- launch ----------------

extern "C" void kernel_launch(void* const* d_in, const int* in_sizes, int n_in,
                              void* d_out, int out_size, void* d_ws, size_t ws_size,
                              hipStream_t stream) {
    const float* x  = (const float*)d_in[0];
    const int* edge = (const int*)d_in[1];
    const float* W1 = (const float*)d_in[2];
    const float* b1 = (const float*)d_in[3];
    const float* W2 = (const float*)d_in[4];
    const float* b2 = (const float*)d_in[5];
    const float* W3 = (const float*)d_in[6];
    const float* b3 = (const float*)d_in[7];
    float* out = (float*)d_out;

    const int* src = edge;
    const int* dst = edge + N_EDGES;

    // workspace layout (float-element offsets)
    float* ws    = (float*)d_ws;
    float* dinv  = ws;                                   // N
    int*   rowp  = (int*)(ws + 100000);                  // N+1 (alloc 100352)
    int*   btot  = (int*)(ws + 200352);                  // 391 (alloc 512)
    int*   bbase = (int*)(ws + 200864);                  // 391 (alloc 512)
    int*   bcnt  = (int*)(ws + 201376);                  // 391*391=152881 (alloc 153600)
    int2*  sedge = (int2*)(ws + 354976);                 // E*2 ints -> ends 3554976
    unsigned char*  X8 = (unsigned char*)(ws + 3554976);     // [NPAD][128] fp8 -> 3202048 f
    unsigned short* B1 = (unsigned short*)(ws + 6757024);    // [NPAD][128] bf16 -> 6404096 f
    unsigned short* B2 = (unsigned short*)(ws + 13161120);   // [NPAD][256] bf16 -> 12808192 f
    unsigned char*  Q2 = (unsigned char*)(ws + 25969312);    // [NPAD][128] fp8 -> 3202048 f
    unsigned short* Wt1 = (unsigned short*)(ws + 29171360);  // [256][128]
    unsigned short* Wt2 = Wt1 + 128 * 256;                   // [128][256]
    unsigned short* Wt3 = Wt2 + 256 * 128;                   // [64][128]
    int*   part  = (int*)B2;   // scratch reuse: consumed before gemm1 writes B2

    const int BT = 256;
    int gRows = (N_NODES + 63) / 64;   // 1563

    // --- bucket counts (reads dst once; LDS-only atomics) ---
    edge_count_kernel<<<NBLK_P, 1024, 0, stream>>>(dst, bcnt);

    // --- bucket scans + partition (packed 32-bit records) ---
    bucket_scan_kernel<<<NBUCK, 64, 0, stream>>>(bcnt, btot);
    bbase_scan_kernel<<<1, 512, 0, stream>>>(btot, bbase);
    part_scatter_kernel<<<NBLK_P, 1024, 0, stream>>>(src, dst, bcnt, bbase, part);

    // --- per-bucket degrees -> rowp + dinv; then coalesced CSR scatter ---
    bucket_deg_kernel<<<NBUCK, 512, 0, stream>>>(part, bbase, btot, rowp, dinv);
    final_scatter_lds_kernel<<<NBUCK, 512, 0, stream>>>(part, dinv, rowp, bbase, btot, sedge);

    // --- conversions ---
    cvt_x_kernel<<<(int)(((long)N_NODES * 128 / 4 + BT - 1) / BT), BT, 0, stream>>>(x, X8);
    cvt_w_all_kernel<<<(73728 + BT - 1) / BT, BT, 0, stream>>>(W1, W2, W3, Wt1, Wt2, Wt3);

    // --- layer 1: agg(x fp8) [X8->B1 bf16], gemm 128->256 +b1 +relu [B1->B2 bf16] ---
    agg_csr_kernel<128, false, false, false, false><<<N_NODES, 64, 0, stream>>>(
        X8, dinv, rowp, sedge, nullptr, B1);
    gemm_mfma_kernel<128, 256, true, true, false><<<gRows, BT, 0, stream>>>(
        B1, Wt1, b1, B2, N_NODES);

    // --- layer 2: gemm 256->128 [B2->Q2 fp8], agg +b2 +relu [Q2->B1 bf16] ---
    gemm_mfma_kernel<256, 128, false, false, true><<<gRows, BT, 0, stream>>>(
        B2, Wt2, nullptr, Q2, N_NODES);
    agg_csr_kernel<128, true, true, false, false><<<N_NODES, 64, 0, stream>>>(
        Q2, dinv, rowp, sedge, b2, B1);

    // --- layer 3: gemm 128->64 [B1->Q2 fp8], agg +b3 +relu +logsm [Q2->out f32] ---
    gemm_mfma_kernel<128, 64, false, false, true><<<gRows, BT, 0, stream>>>(
        B1, Wt3, nullptr, Q2, N_NODES);
    agg_csr_kernel<64, true, true, true, true><<<N_NODES, 64, 0, stream>>>(
        Q2, dinv, rowp, sedge, b3, out);

    (void)in_sizes; (void)n_in; (void)out_size; (void)ws_size;
}

// Round 17
// 263.884 us; speedup vs baseline: 1.1608x; 1.0444x over previous
//
#include <hip/hip_runtime.h>
#include <math.h>

#define N_NODES 100000
#define N_EDGES 1600000
#define CHUNK 4096
#define NBLK_P ((N_EDGES + CHUNK - 1) / CHUNK)  // 391
#define NPAD 100064                          // 64-row padded for GEMM staging
#define BSHIFT 8                             // 256 nodes per bucket
#define NBUCK ((N_NODES + 255) / 256)        // 391 buckets
#define BCAP 6144                            // LDS record capacity per bucket

typedef __attribute__((ext_vector_type(8))) short bf16x8;
typedef __attribute__((ext_vector_type(4))) float f32x4;
typedef __attribute__((ext_vector_type(2))) float f32x2;

__device__ __forceinline__ unsigned short f2bf(float f) {
    unsigned int u = __builtin_bit_cast(unsigned int, f);
    u += 0x7fffu + ((u >> 16) & 1u);          // RNE
    return (unsigned short)(u >> 16);
}
// fp8 e4m3 (OCP) encode/decode via gfx950 hardware cvt
__device__ __forceinline__ unsigned char f2fp8(float f) {
    return (unsigned char)(__builtin_amdgcn_cvt_pk_fp8_f32(f, f, 0, false) & 0xff);
}
__device__ __forceinline__ f32x2 fp8x2f(unsigned short u) {   // 2 fp8 -> 2 f32
    return __builtin_amdgcn_cvt_pk_f32_fp8((int)u, false);
}
__device__ __forceinline__ float fp8f(unsigned char u) {
    return __builtin_amdgcn_cvt_f32_fp8((int)u, 0);
}
// packed edge record: src (17b) | dinv_q15 (15b)
__device__ __forceinline__ float decw(unsigned int r) {
    return (float)(r >> 17) * (1.0f / 32767.0f);
}

// ---------------- bucket count only (LDS atomics) ----------------

__global__ __launch_bounds__(1024) void edge_count_kernel(const int* __restrict__ dst,
                                                          int* __restrict__ bcnt) {
    __shared__ int lh[NBUCK];
    int tid = threadIdx.x;
    if (tid < NBUCK) lh[tid] = 0;
    __syncthreads();
    long base = (long)blockIdx.x * CHUNK;
#pragma unroll
    for (int p = 0; p < CHUNK; p += 1024) {
        long e = base + p + tid;
        if (e < N_EDGES) atomicAdd(&lh[dst[e] >> BSHIFT], 1);
    }
    __syncthreads();
    if (tid < NBUCK) bcnt[tid * NBLK_P + blockIdx.x] = lh[tid];
}

// ---------------- bucket scan over blocks (one wave per bucket) ----------------

__global__ void bucket_scan_kernel(int* __restrict__ bcnt, int* __restrict__ btot) {
    int bu = blockIdx.x, lane = threadIdx.x;   // 64 threads
    int base = 0;
    for (int i0 = 0; i0 < NBLK_P; i0 += 64) {
        int i = i0 + lane;
        int v = (i < NBLK_P) ? bcnt[bu * NBLK_P + i] : 0;
        int orig = v;
#pragma unroll
        for (int off = 1; off < 64; off <<= 1) {
            int t = __shfl_up(v, off);
            if (lane >= off) v += t;
        }
        if (i < NBLK_P) bcnt[bu * NBLK_P + i] = base + v - orig;
        base += __shfl(v, 63);
    }
    if (lane == 0) btot[bu] = base;
}

// parallel exclusive scan over NBUCK totals (single 512-thread block)
__global__ void bbase_scan_kernel(const int* __restrict__ btot, int* __restrict__ bbase) {
    __shared__ int tmp[512];
    int i = threadIdx.x;
    int v = (i < NBUCK) ? btot[i] : 0;
    tmp[i] = v;
    __syncthreads();
    for (int off = 1; off < 512; off <<= 1) {
        int t = (i >= off) ? tmp[i - off] : 0;
        __syncthreads();
        tmp[i] += t;
        __syncthreads();
    }
    if (i < NBUCK) bbase[i] = tmp[i] - v;
}

// ---------------- partition edges; record packed: src | (d&255)<<17 ----------------

__global__ __launch_bounds__(1024) void part_scatter_kernel(
        const int* __restrict__ src, const int* __restrict__ dst,
        const int* __restrict__ bcnt, const int* __restrict__ bbase,
        int* __restrict__ part) {
    __shared__ int lh[NBUCK];
    int tid = threadIdx.x;
    if (tid < NBUCK) lh[tid] = 0;
    __syncthreads();
    long base = (long)blockIdx.x * CHUNK;
#pragma unroll
    for (int p = 0; p < CHUNK; p += 1024) {
        long e = base + p + tid;
        if (e < N_EDGES) {
            int s = src[e], d = dst[e];
            int bu = d >> BSHIFT;
            int lr = atomicAdd(&lh[bu], 1);
            int pos = bbase[bu] + bcnt[bu * NBLK_P + blockIdx.x] + lr;
            part[pos] = s | ((d & 255) << 17);
        }
    }
}

// ---------------- per-bucket degrees -> rowp + dinv (LDS count + local scan) ----------------

__global__ __launch_bounds__(512) void bucket_deg_kernel(
        const int* __restrict__ part, const int* __restrict__ bbase,
        const int* __restrict__ btot, int* __restrict__ rowp,
        float* __restrict__ dinv) {
    __shared__ int lcnt[256];
    __shared__ int lscan[256];
    int b = blockIdx.x;
    int node0 = b << BSHIFT;
    int start = bbase[b];
    int cnt = btot[b];
    int tid = threadIdx.x;
    if (tid < 256) lcnt[tid] = 0;
    __syncthreads();
    for (int e = tid; e < cnt; e += 512)
        atomicAdd(&lcnt[part[start + e] >> 17], 1);
    __syncthreads();
    int v = 0;
    if (tid < 256) { v = lcnt[tid]; lscan[tid] = v; }
    __syncthreads();
    for (int off = 1; off < 256; off <<= 1) {
        int t = (tid < 256 && tid >= off) ? lscan[tid - off] : 0;
        __syncthreads();
        if (tid < 256) lscan[tid] += t;
        __syncthreads();
    }
    if (tid < 256) {
        int n = node0 + tid;
        if (n < N_NODES) {
            rowp[n] = start + lscan[tid] - v;      // exclusive prefix
            dinv[n] = rsqrtf(1.0f + (float)v);     // +1 self-loop
        }
    }
    if (b == NBUCK - 1 && tid == 0) rowp[N_NODES] = N_EDGES;
}

// ---------------- final scatter, LDS-staged per bucket: coalesced 4B records ----------------
// sedge[e] = src | (round(dinv[src]*32767) << 17)

__global__ __launch_bounds__(512) void final_scatter_lds_kernel(
        const int* __restrict__ part, const float* __restrict__ dinv,
        const int* __restrict__ rowp, const int* __restrict__ bbase,
        const int* __restrict__ btot, unsigned int* __restrict__ sedge) {
    __shared__ int lcurs[256];
    __shared__ unsigned int buf[BCAP];
    int b = blockIdx.x;
    int node0 = b << BSHIFT;
    int start = bbase[b];
    int cnt = btot[b];
    int tid = threadIdx.x;
    if (tid < 256) {
        int n = node0 + tid;
        lcurs[tid] = (n < N_NODES) ? (rowp[n] - start) : cnt;
    }
    __syncthreads();
    for (int e = tid; e < cnt; e += 512) {
        int r = part[start + e];
        int s = r & 0x1FFFF;
        int lpos = atomicAdd(&lcurs[r >> 17], 1);
        unsigned int q = (unsigned int)(dinv[s] * 32767.0f + 0.5f);
        unsigned int rec = (unsigned int)s | (q << 17);
        if (lpos < BCAP) buf[lpos] = rec;
        else sedge[start + lpos] = rec;   // statistical-impossibility fallback
    }
    __syncthreads();
    int lim = min(cnt, BCAP);
    for (int e = tid; e < lim; e += 512)
        sedge[start + e] = buf[e];
}

// ---------------- fused conversions: x -> fp8 table, weights -> bf16 transposed ----------------

#define CVT_X_ITEMS 3200000   // N*128/4

__global__ void cvt_all_kernel(const float* __restrict__ x, unsigned char* __restrict__ xb,
                               const float* __restrict__ W1, const float* __restrict__ W2,
                               const float* __restrict__ W3,
                               unsigned short* __restrict__ Wt1,
                               unsigned short* __restrict__ Wt2,
                               unsigned short* __restrict__ Wt3) {
    long i = (long)blockIdx.x * blockDim.x + threadIdx.x;
    if (i < CVT_X_ITEMS) {
        float4 v = ((const float4*)x)[i];
        int p0 = __builtin_amdgcn_cvt_pk_fp8_f32(v.x, v.y, 0, false);
        int p1 = __builtin_amdgcn_cvt_pk_fp8_f32(v.z, v.w, 0, false);
        ((unsigned int*)xb)[i] = ((unsigned int)p0 & 0xffffu) | ((unsigned int)p1 << 16);
        return;
    }
    int j = (int)(i - CVT_X_ITEMS);
    if (j < 32768) {                       // W1: [128][256]
        int k = j >> 8, m = j & 255;
        Wt1[m * 128 + k] = f2bf(W1[j]);
    } else if (j < 65536) {                // W2: [256][128]
        int t = j - 32768;
        int k = t >> 7, m = t & 127;
        Wt2[m * 256 + k] = f2bf(W2[t]);
    } else if (j < 73728) {                // W3: [128][64]
        int t = j - 65536;
        int k = t >> 6, m = t & 63;
        Wt3[m * 128 + k] = f2bf(W3[t]);
    }
}

// ---------------- CSR gather aggregation (fp8 in, bf16/f32 out) ----------------
// one wave per dst node; 4B packed edge records; 8 gathers in flight; fp32 accum

template<int C, bool BIAS, bool RELU, bool LOGSM, bool OUTF32>
__global__ __launch_bounds__(64) void agg_csr_kernel(
                               const unsigned char* __restrict__ h8,
                               const float* __restrict__ dinv,
                               const int* __restrict__ rowptr,
                               const unsigned int* __restrict__ sedge,
                               const float* __restrict__ bias, void* __restrict__ outv) {
    constexpr int V = C / 64;  // 2 for C=128, 1 for C=64
    int gw = blockIdx.x;
    int lane = threadIdx.x;
    if (gw >= N_NODES) return;

    float di = dinv[gw];
    int st = rowptr[gw];
    int cnt = rowptr[gw + 1] - st;
    float a0, a1 = 0.0f;
    if constexpr (V == 2) {
        unsigned short u = ((const unsigned short*)(h8 + (long)gw * C))[lane];
        f32x2 f = fp8x2f(u);
        a0 = di * f.x; a1 = di * f.y;
    } else {
        a0 = di * fp8f(h8[(long)gw * C + lane]);
    }

    int k = 0;
    // 8-deep gather block
    for (; k + 8 <= cnt; k += 8) {
        unsigned int r[8];
#pragma unroll
        for (int j = 0; j < 8; ++j) r[j] = sedge[st + k + j];
        if constexpr (V == 2) {
            unsigned short u[8];
#pragma unroll
            for (int j = 0; j < 8; ++j)
                u[j] = ((const unsigned short*)(h8 + (long)(r[j] & 0x1FFFF) * C))[lane];
#pragma unroll
            for (int j = 0; j < 8; ++j) {
                float w = decw(r[j]);
                f32x2 f = fp8x2f(u[j]);
                a0 += w * f.x; a1 += w * f.y;
            }
        } else {
            unsigned char u[8];
#pragma unroll
            for (int j = 0; j < 8; ++j)
                u[j] = h8[(long)(r[j] & 0x1FFFF) * C + lane];
#pragma unroll
            for (int j = 0; j < 8; ++j)
                a0 += decw(r[j]) * fp8f(u[j]);
        }
    }
    // 4-deep
    for (; k + 4 <= cnt; k += 4) {
        unsigned int r[4];
#pragma unroll
        for (int j = 0; j < 4; ++j) r[j] = sedge[st + k + j];
        if constexpr (V == 2) {
            unsigned short u[4];
#pragma unroll
            for (int j = 0; j < 4; ++j)
                u[j] = ((const unsigned short*)(h8 + (long)(r[j] & 0x1FFFF) * C))[lane];
#pragma unroll
            for (int j = 0; j < 4; ++j) {
                float w = decw(r[j]);
                f32x2 f = fp8x2f(u[j]);
                a0 += w * f.x; a1 += w * f.y;
            }
        } else {
            unsigned char u[4];
#pragma unroll
            for (int j = 0; j < 4; ++j)
                u[j] = h8[(long)(r[j] & 0x1FFFF) * C + lane];
#pragma unroll
            for (int j = 0; j < 4; ++j)
                a0 += decw(r[j]) * fp8f(u[j]);
        }
    }
    // tail
    for (; k < cnt; ++k) {
        unsigned int r = sedge[st + k];
        float w = decw(r);
        if constexpr (V == 2) {
            unsigned short u = ((const unsigned short*)(h8 + (long)(r & 0x1FFFF) * C))[lane];
            f32x2 f = fp8x2f(u);
            a0 += w * f.x; a1 += w * f.y;
        } else {
            a0 += w * fp8f(h8[(long)(r & 0x1FFFF) * C + lane]);
        }
    }

    a0 *= di; a1 *= di;
    if constexpr (BIAS) {
        if constexpr (V == 2) { a0 += bias[lane * 2]; a1 += bias[lane * 2 + 1]; }
        else a0 += bias[lane];
    }
    if constexpr (RELU) { a0 = fmaxf(a0, 0.0f); a1 = fmaxf(a1, 0.0f); }
    if constexpr (LOGSM) {  // V==1 only
        float m = a0;
#pragma unroll
        for (int o = 32; o > 0; o >>= 1) m = fmaxf(m, __shfl_xor(m, o));
        float e = expf(a0 - m), s = e;
#pragma unroll
        for (int o = 32; o > 0; o >>= 1) s += __shfl_xor(s, o);
        a0 = a0 - m - logf(s);
    }
    if constexpr (OUTF32) {
        float* out = (float*)outv;
        if constexpr (V == 2) {
            float2 r; r.x = a0; r.y = a1;
            *(float2*)(out + (long)gw * C + lane * 2) = r;
        } else {
            out[(long)gw * C + lane] = a0;
        }
    } else {
        unsigned short* out = (unsigned short*)outv;
        if constexpr (V == 2) {
            unsigned int up = (unsigned int)f2bf(a0) | ((unsigned int)f2bf(a1) << 16);
            ((unsigned int*)(out + (long)gw * C))[lane] = up;
        } else {
            out[(long)gw * C + lane] = f2bf(a0);
        }
    }
}

// ---------------- bf16 MFMA GEMM, 64 x full-M tile; bf16 or fp8 output ----------------
template<int K, int M, bool BIAS, bool RELU, bool OUT8>
__global__ __launch_bounds__(256) void gemm_mfma_kernel(
        const unsigned short* __restrict__ A,   // [NPAD][K] bf16
        const unsigned short* __restrict__ Bt,  // [M][K] bf16
        const float* __restrict__ bias,         // [M]
        void* __restrict__ Cv,                  // [NPAD][M] bf16 or fp8
        int N) {
    constexpr int KC = K / 8;                    // 16B chunks per row
    constexpr int NT = M / 64;                   // col subtiles per wave (M/4/16)
    __shared__ unsigned short As[64 * K];

    int tid = threadIdx.x;
    int row0 = blockIdx.x * 64;
    const unsigned short* Ap = A + (long)row0 * K;

    // stage A panel; LDS byte = (c*16) ^ ((row&7)<<4)
    for (int c = tid; c < 64 * KC; c += 256) {
        int r = c / KC;
        unsigned int swz = ((unsigned int)c * 16u) ^ ((unsigned int)(r & 7) << 4);
        *(bf16x8*)((char*)As + swz) = *(const bf16x8*)(Ap + c * 8);
    }
    __syncthreads();

    int lane = tid & 63;
    int wv = tid >> 6;
    int lr = lane & 15;
    int kg = lane >> 4;                 // k-group: k = kg*8 + j
    int colbase = wv * (M / 4);

    const unsigned short* bp[NT];
#pragma unroll
    for (int ni = 0; ni < NT; ++ni)
        bp[ni] = Bt + (size_t)(colbase + ni * 16 + lr) * K + kg * 8;

    f32x4 acc[4][NT] = {};

    for (int k0 = 0; k0 < K; k0 += 32) {
        bf16x8 a[4], b[NT];
#pragma unroll
        for (int mi = 0; mi < 4; ++mi) {
            int r = mi * 16 + lr;
            unsigned int byteo = (unsigned int)((r * K + k0 + kg * 8) * 2);
            byteo ^= (unsigned int)((r & 7) << 4);
            a[mi] = *(const bf16x8*)((const char*)As + byteo);
        }
#pragma unroll
        for (int ni = 0; ni < NT; ++ni)
            b[ni] = *(const bf16x8*)(bp[ni] + k0);
#pragma unroll
        for (int mi = 0; mi < 4; ++mi)
#pragma unroll
            for (int ni = 0; ni < NT; ++ni)
                acc[mi][ni] = __builtin_amdgcn_mfma_f32_16x16x32_bf16(
                    a[mi], b[ni], acc[mi][ni], 0, 0, 0);
    }

    // epilogue: C/D layout col=lane&15, row=(lane>>4)*4+i
#pragma unroll
    for (int mi = 0; mi < 4; ++mi) {
#pragma unroll
        for (int ni = 0; ni < NT; ++ni) {
            int col = colbase + ni * 16 + lr;
            float bv = BIAS ? bias[col] : 0.0f;
#pragma unroll
            for (int i = 0; i < 4; ++i) {
                int row = row0 + mi * 16 + kg * 4 + i;
                if (row < N) {
                    float v = acc[mi][ni][i] + bv;
                    if (RELU) v = fmaxf(v, 0.0f);
                    if constexpr (OUT8)
                        ((unsigned char*)Cv)[(long)row * M + col] = f2fp8(v);
                    else
                        ((unsigned short*)Cv)[(long)row * M + col] = f2bf(v);
                }
            }
        }
    }
}

// ---------------- launch ----------------

extern "C" void kernel_launch(void* const* d_in, const int* in_sizes, int n_in,
                              void* d_out, int out_size, void* d_ws, size_t ws_size,
                              hipStream_t stream) {
    const float* x  = (const float*)d_in[0];
    const int* edge = (const int*)d_in[1];
    const float* W1 = (const float*)d_in[2];
    const float* b1 = (const float*)d_in[3];
    const float* W2 = (const float*)d_in[4];
    const float* b2 = (const float*)d_in[5];
    const float* W3 = (const float*)d_in[6];
    const float* b3 = (const float*)d_in[7];
    float* out = (float*)d_out;

    const int* src = edge;
    const int* dst = edge + N_EDGES;

    // workspace layout (float-element offsets)
    float* ws    = (float*)d_ws;
    float* dinv  = ws;                                   // N
    int*   rowp  = (int*)(ws + 100000);                  // N+1 (alloc 100352)
    int*   btot  = (int*)(ws + 200352);                  // 391 (alloc 512)
    int*   bbase = (int*)(ws + 200864);                  // 391 (alloc 512)
    int*   bcnt  = (int*)(ws + 201376);                  // 391*391=152881 (alloc 153600)
    unsigned int* sedge = (unsigned int*)(ws + 354976);  // E u32 -> ends 1954976
    unsigned char*  X8 = (unsigned char*)(ws + 1954976);     // [NPAD][128] fp8 -> 3202048 f
    unsigned short* B1 = (unsigned short*)(ws + 5157024);    // [NPAD][128] bf16 -> 6404096 f
    unsigned short* B2 = (unsigned short*)(ws + 11561120);   // [NPAD][256] bf16 -> 12808192 f
    unsigned char*  Q2 = (unsigned char*)(ws + 24369312);    // [NPAD][128] fp8 -> 3202048 f
    unsigned short* Wt1 = (unsigned short*)(ws + 27571360);  // [256][128]
    unsigned short* Wt2 = Wt1 + 128 * 256;                   // [128][256]
    unsigned short* Wt3 = Wt2 + 256 * 128;                   // [64][128]
    int*   part  = (int*)B2;   // scratch reuse: consumed before gemm1 writes B2

    const int BT = 256;
    int gRows = (N_NODES + 63) / 64;   // 1563

    // --- bucket counts (reads dst once; LDS-only atomics) ---
    edge_count_kernel<<<NBLK_P, 1024, 0, stream>>>(dst, bcnt);

    // --- bucket scans + partition (packed 32-bit records) ---
    bucket_scan_kernel<<<NBUCK, 64, 0, stream>>>(bcnt, btot);
    bbase_scan_kernel<<<1, 512, 0, stream>>>(btot, bbase);
    part_scatter_kernel<<<NBLK_P, 1024, 0, stream>>>(src, dst, bcnt, bbase, part);

    // --- per-bucket degrees -> rowp + dinv; then coalesced CSR scatter (4B recs) ---
    bucket_deg_kernel<<<NBUCK, 512, 0, stream>>>(part, bbase, btot, rowp, dinv);
    final_scatter_lds_kernel<<<NBUCK, 512, 0, stream>>>(part, dinv, rowp, bbase, btot, sedge);

    // --- fused conversions ---
    cvt_all_kernel<<<(int)((CVT_X_ITEMS + 73728 + BT - 1) / BT), BT, 0, stream>>>(
        x, X8, W1, W2, W3, Wt1, Wt2, Wt3);

    // --- layer 1: agg(x fp8) [X8->B1 bf16], gemm 128->256 +b1 +relu [B1->B2 bf16] ---
    agg_csr_kernel<128, false, false, false, false><<<N_NODES, 64, 0, stream>>>(
        X8, dinv, rowp, sedge, nullptr, B1);
    gemm_mfma_kernel<128, 256, true, true, false><<<gRows, BT, 0, stream>>>(
        B1, Wt1, b1, B2, N_NODES);

    // --- layer 2: gemm 256->128 [B2->Q2 fp8], agg +b2 +relu [Q2->B1 bf16] ---
    gemm_mfma_kernel<256, 128, false, false, true><<<gRows, BT, 0, stream>>>(
        B2, Wt2, nullptr, Q2, N_NODES);
    agg_csr_kernel<128, true, true, false, false><<<N_NODES, 64, 0, stream>>>(
        Q2, dinv, rowp, sedge, b2, B1);

    // --- layer 3: gemm 128->64 [B1->Q2 fp8], agg +b3 +relu +logsm [Q2->out f32] ---
    gemm_mfma_kernel<128, 64, false, false, true><<<gRows, BT, 0, stream>>>(
        B1, Wt3, nullptr, Q2, N_NODES);
    agg_csr_kernel<64, true, true, true, true><<<N_NODES, 64, 0, stream>>>(
        Q2, dinv, rowp, sedge, b3, out);

    (void)in_sizes; (void)n_in; (void)out_size; (void)ws_size;
}